// Round 1
// baseline (896.801 us; speedup 1.0000x reference)
//
#include <hip/hip_runtime.h>
#include <hip/hip_bf16.h>
#include <cstdint>

#define NN 100000
#define NE 1600000
#define NC 128

constexpr int SCAN_SEG = 1024;
constexpr int NB = (NN + SCAN_SEG - 1) / SCAN_SEG; // 98

// ---------------- degree / norm ----------------

__global__ __launch_bounds__(256) void k_init(float* __restrict__ deg, int* __restrict__ cnt) {
    int i = blockIdx.x * 256 + threadIdx.x;
    if (i < NN) { deg[i] = 1.0f; cnt[i] = 0; }   // self-loop weight 1 pre-added
}

__global__ __launch_bounds__(256) void k_degcount(const int* __restrict__ dst, const float* __restrict__ w,
                                                  float* __restrict__ deg, int* __restrict__ cnt) {
    int e = blockIdx.x * 256 + threadIdx.x;
    if (e < NE) {
        int d = dst[e];
        unsafeAtomicAdd(&deg[d], w[e]);
        atomicAdd(&cnt[d], 1);
    }
}

__global__ __launch_bounds__(256) void k_dinv(const float* __restrict__ deg, float* __restrict__ dinv) {
    int i = blockIdx.x * 256 + threadIdx.x;
    if (i < NN) {
        float dg = deg[i];
        dinv[i] = (dg > 0.0f) ? (1.0f / sqrtf(fmaxf(dg, 1e-12f))) : 0.0f;
    }
}

// ---------------- exclusive scan of cnt -> rowstart ----------------

__global__ __launch_bounds__(256) void k_scan1(const int* __restrict__ cnt, int* __restrict__ bsum) {
    __shared__ int sdata[256];
    int b = blockIdx.x, t = threadIdx.x;
    int base = b * SCAN_SEG + t * 4;
    int s = 0;
    #pragma unroll
    for (int j = 0; j < 4; ++j) { int idx = base + j; if (idx < NN) s += cnt[idx]; }
    sdata[t] = s; __syncthreads();
    for (int off = 128; off > 0; off >>= 1) {
        if (t < off) sdata[t] += sdata[t + off];
        __syncthreads();
    }
    if (t == 0) bsum[b] = sdata[0];
}

__global__ void k_scan2(int* __restrict__ bsum, int* __restrict__ rowstart) {
    if (threadIdx.x == 0 && blockIdx.x == 0) {
        int run = 0;
        for (int i = 0; i < NB; ++i) { int v = bsum[i]; bsum[i] = run; run += v; }
        rowstart[NN] = run;  // == NE
    }
}

__global__ __launch_bounds__(256) void k_scan3(int* __restrict__ cnt, const int* __restrict__ bsum,
                                               int* __restrict__ rowstart) {
    __shared__ int sdata[256];
    int b = blockIdx.x, t = threadIdx.x;
    int base = b * SCAN_SEG + t * 4;
    int v[4]; int vsum = 0;
    #pragma unroll
    for (int j = 0; j < 4; ++j) { int idx = base + j; v[j] = (idx < NN) ? cnt[idx] : 0; vsum += v[j]; }
    sdata[t] = vsum; __syncthreads();
    int incl = vsum;
    for (int off = 1; off < 256; off <<= 1) {
        int add = (t >= off) ? sdata[t - off] : 0;
        __syncthreads();
        incl += add;
        sdata[t] = incl;
        __syncthreads();
    }
    int run = bsum[b] + (incl - vsum);
    #pragma unroll
    for (int j = 0; j < 4; ++j) {
        int idx = base + j;
        if (idx < NN) { rowstart[idx] = run; run += v[j]; cnt[idx] = 0; }  // zero cnt for reuse as cursor
    }
}

// ---------------- CSR fill ----------------

__global__ __launch_bounds__(256) void k_fill(const int* __restrict__ src, const int* __restrict__ dst,
                                              const float* __restrict__ w, const float* __restrict__ dinv,
                                              const int* __restrict__ rowstart, int* __restrict__ cnt,
                                              int* __restrict__ csrc, float* __restrict__ cnrm) {
    int e = blockIdx.x * 256 + threadIdx.x;
    if (e < NE) {
        int s = src[e], d = dst[e];
        int pos = rowstart[d] + atomicAdd(&cnt[d], 1);
        csrc[pos] = s;
        cnrm[pos] = dinv[s] * w[e] * dinv[d];
    }
}

// ---------------- GEMM: H = X @ W  (X [NN,128] f32, W [128,128] f32) ----------------
// block 256 = 8 row-threads x 32 col-threads; tile 64 rows x 128 cols; thread 8 rows x 4 cols.

__global__ __launch_bounds__(256) void k_gemm(const float* __restrict__ Xg, const float* __restrict__ Wg,
                                              float* __restrict__ Hg) {
    __shared__ float Ws[64][128];  // 32 KB: k-chunk x all cols
    __shared__ float Xs[64][64];   // 16 KB: rows x k-chunk

    int t  = threadIdx.x;
    int tx = t & 31;       // col group
    int ty = t >> 5;       // row group 0..7
    int c0 = tx * 4;
    int rowBase = blockIdx.x * 64;

    float4 acc[8];
    #pragma unroll
    for (int r = 0; r < 8; ++r) acc[r] = make_float4(0.f, 0.f, 0.f, 0.f);

    for (int kc = 0; kc < 128; kc += 64) {
        // load W chunk: 64x128 floats
        #pragma unroll
        for (int j = 0; j < 8; ++j) {
            int l  = (t + j * 256) * 4;
            int kr = l >> 7;
            int cc = l & 127;
            *(float4*)&Ws[kr][cc] = *(const float4*)&Wg[(kc + kr) * NC + cc];
        }
        // load X chunk: 64x64 floats
        #pragma unroll
        for (int j = 0; j < 4; ++j) {
            int l  = (t + j * 256) * 4;
            int rr = l >> 6;
            int kk = l & 63;
            int gr = rowBase + rr; if (gr > NN - 1) gr = NN - 1;
            *(float4*)&Xs[rr][kk] = *(const float4*)&Xg[(size_t)gr * NC + kc + kk];
        }
        __syncthreads();

        #pragma unroll 4
        for (int kk = 0; kk < 64; kk += 4) {
            float4 wv0 = *(const float4*)&Ws[kk + 0][c0];
            float4 wv1 = *(const float4*)&Ws[kk + 1][c0];
            float4 wv2 = *(const float4*)&Ws[kk + 2][c0];
            float4 wv3 = *(const float4*)&Ws[kk + 3][c0];
            #pragma unroll
            for (int r = 0; r < 8; ++r) {
                float4 xv = *(const float4*)&Xs[ty * 8 + r][kk];
                acc[r].x = fmaf(xv.x, wv0.x, acc[r].x); acc[r].y = fmaf(xv.x, wv0.y, acc[r].y);
                acc[r].z = fmaf(xv.x, wv0.z, acc[r].z); acc[r].w = fmaf(xv.x, wv0.w, acc[r].w);
                acc[r].x = fmaf(xv.y, wv1.x, acc[r].x); acc[r].y = fmaf(xv.y, wv1.y, acc[r].y);
                acc[r].z = fmaf(xv.y, wv1.z, acc[r].z); acc[r].w = fmaf(xv.y, wv1.w, acc[r].w);
                acc[r].x = fmaf(xv.z, wv2.x, acc[r].x); acc[r].y = fmaf(xv.z, wv2.y, acc[r].y);
                acc[r].z = fmaf(xv.z, wv2.z, acc[r].z); acc[r].w = fmaf(xv.z, wv2.w, acc[r].w);
                acc[r].x = fmaf(xv.w, wv3.x, acc[r].x); acc[r].y = fmaf(xv.w, wv3.y, acc[r].y);
                acc[r].z = fmaf(xv.w, wv3.z, acc[r].z); acc[r].w = fmaf(xv.w, wv3.w, acc[r].w);
            }
        }
        __syncthreads();
    }

    #pragma unroll
    for (int r = 0; r < 8; ++r) {
        int gr = rowBase + ty * 8 + r;
        if (gr < NN) *(float4*)&Hg[(size_t)gr * NC + c0] = acc[r];
    }
}

// ---------------- aggregation: out[d] = sum_e nrm*H[src] + dinv[d]^2*H[d] + b ----------------
// one 64-lane wave per node, each lane owns 2 channels (float2)

template <int RELU>
__global__ __launch_bounds__(256) void k_agg(const float* __restrict__ H, const int* __restrict__ rs,
                                             const int* __restrict__ csrc, const float* __restrict__ cnrm,
                                             const float* __restrict__ dinv, const float* __restrict__ bias,
                                             float* __restrict__ out) {
    int wid  = (blockIdx.x * 256 + threadIdx.x) >> 6;
    int lane = threadIdx.x & 63;
    if (wid >= NN) return;
    int node = wid;

    float di = dinv[node];
    float2 acc;
    {
        float2 hv = *(const float2*)&H[(size_t)node * NC + lane * 2];
        float s = di * di;
        acc.x = hv.x * s; acc.y = hv.y * s;
    }
    int p0 = rs[node], p1 = rs[node + 1];
    for (int p = p0; p < p1; ++p) {
        int   s  = csrc[p];
        float nw = cnrm[p];
        float2 hv = *(const float2*)&H[(size_t)s * NC + lane * 2];
        acc.x = fmaf(nw, hv.x, acc.x);
        acc.y = fmaf(nw, hv.y, acc.y);
    }
    float2 bv = *(const float2*)&bias[lane * 2];
    acc.x += bv.x; acc.y += bv.y;
    if (RELU) { acc.x = fmaxf(acc.x, 0.f); acc.y = fmaxf(acc.y, 0.f); }
    *(float2*)&out[(size_t)node * NC + lane * 2] = acc;
}

// ---------------- launch ----------------

static inline size_t alignup(size_t x) { return (x + 255) & ~(size_t)255; }

extern "C" void kernel_launch(void* const* d_in, const int* in_sizes, int n_in,
                              void* d_out, int out_size, void* d_ws, size_t ws_size,
                              hipStream_t stream) {
    const float* X  = (const float*)d_in[0];
    const int*   ei = (const int*)d_in[1];          // [2, NE]: row0 = src, row1 = dst
    const float* ew = (const float*)d_in[2];
    const float* W1 = (const float*)d_in[3]; const float* b1 = (const float*)d_in[4];
    const float* W2 = (const float*)d_in[5]; const float* b2 = (const float*)d_in[6];
    const float* W3 = (const float*)d_in[7]; const float* b3 = (const float*)d_in[8];
    float* out = (float*)d_out;

    const int* srcp = ei;
    const int* dstp = ei + NE;

    // workspace carve
    char* w = (char*)d_ws;
    size_t need = 0;
    auto carve = [&](size_t bytes) { char* p = w + need; need += alignup(bytes); return p; };
    float* deg      = (float*)carve(NN * 4);
    float* dinv     = (float*)carve(NN * 4);
    int*   cnt      = (int*)  carve(NN * 4);
    int*   rowstart = (int*)  carve((NN + 1) * 4);
    int*   bsum     = (int*)  carve(NB * 4);
    int*   csrc     = (int*)  carve((size_t)NE * 4);
    float* cnrm     = (float*)carve((size_t)NE * 4);
    float* H        = (float*)carve((size_t)NN * NC * 4);
    float* A        = (float*)carve((size_t)NN * NC * 4);
    if (need > ws_size) return;  // workspace too small -> visible validation failure

    const int gN = (NN + 255) / 256;
    const int gE = (NE + 255) / 256;
    const int gGemm = (NN + 63) / 64;
    const int gAgg  = (NN * 64 + 255) / 256;  // one wave per node

    // build normalization + CSR (once; reused by all 3 layers)
    k_init<<<gN, 256, 0, stream>>>(deg, cnt);
    k_degcount<<<gE, 256, 0, stream>>>(dstp, ew, deg, cnt);
    k_dinv<<<gN, 256, 0, stream>>>(deg, dinv);
    k_scan1<<<NB, 256, 0, stream>>>(cnt, bsum);
    k_scan2<<<1, 64, 0, stream>>>(bsum, rowstart);
    k_scan3<<<NB, 256, 0, stream>>>(cnt, bsum, rowstart);
    k_fill<<<gE, 256, 0, stream>>>(srcp, dstp, ew, dinv, rowstart, cnt, csrc, cnrm);

    // layer 1
    k_gemm<<<gGemm, 256, 0, stream>>>(X, W1, H);
    k_agg<1><<<gAgg, 256, 0, stream>>>(H, rowstart, csrc, cnrm, dinv, b1, A);
    // layer 2
    k_gemm<<<gGemm, 256, 0, stream>>>(A, W2, H);
    k_agg<1><<<gAgg, 256, 0, stream>>>(H, rowstart, csrc, cnrm, dinv, b2, A);
    // layer 3
    k_gemm<<<gGemm, 256, 0, stream>>>(A, W3, H);
    k_agg<0><<<gAgg, 256, 0, stream>>>(H, rowstart, csrc, cnrm, dinv, b3, out);
}

// Round 2
// 737.916 us; speedup vs baseline: 1.2153x; 1.2153x over previous
//
#include <hip/hip_runtime.h>
#include <hip/hip_bf16.h>
#include <cstdint>

#define NN 100000
#define NE 1600000
#define NC 128

constexpr int SCAN_SEG = 1024;
constexpr int NB = (NN + SCAN_SEG - 1) / SCAN_SEG; // 98

// ---------------- degree / norm ----------------

__global__ __launch_bounds__(256) void k_init(float* __restrict__ deg, int* __restrict__ cnt) {
    int i = blockIdx.x * 256 + threadIdx.x;
    if (i < NN) { deg[i] = 1.0f; cnt[i] = 0; }   // self-loop weight 1 pre-added
}

__global__ __launch_bounds__(256) void k_degcount(const int* __restrict__ dst, const float* __restrict__ w,
                                                  float* __restrict__ deg, int* __restrict__ cnt) {
    int e = blockIdx.x * 256 + threadIdx.x;
    if (e < NE) {
        int d = dst[e];
        unsafeAtomicAdd(&deg[d], w[e]);
        atomicAdd(&cnt[d], 1);
    }
}

__global__ __launch_bounds__(256) void k_dinv(const float* __restrict__ deg, float* __restrict__ dinv) {
    int i = blockIdx.x * 256 + threadIdx.x;
    if (i < NN) {
        float dg = deg[i];
        dinv[i] = (dg > 0.0f) ? (1.0f / sqrtf(fmaxf(dg, 1e-12f))) : 0.0f;
    }
}

// ---------------- exclusive scan of cnt -> rowstart ----------------

__global__ __launch_bounds__(256) void k_scan1(const int* __restrict__ cnt, int* __restrict__ bsum) {
    __shared__ int sdata[256];
    int b = blockIdx.x, t = threadIdx.x;
    int base = b * SCAN_SEG + t * 4;
    int s = 0;
    #pragma unroll
    for (int j = 0; j < 4; ++j) { int idx = base + j; if (idx < NN) s += cnt[idx]; }
    sdata[t] = s; __syncthreads();
    for (int off = 128; off > 0; off >>= 1) {
        if (t < off) sdata[t] += sdata[t + off];
        __syncthreads();
    }
    if (t == 0) bsum[b] = sdata[0];
}

__global__ void k_scan2(int* __restrict__ bsum, int* __restrict__ rowstart) {
    if (threadIdx.x == 0 && blockIdx.x == 0) {
        int run = 0;
        for (int i = 0; i < NB; ++i) { int v = bsum[i]; bsum[i] = run; run += v; }
        rowstart[NN] = run;  // == NE
    }
}

__global__ __launch_bounds__(256) void k_scan3(int* __restrict__ cnt, const int* __restrict__ bsum,
                                               int* __restrict__ rowstart) {
    __shared__ int sdata[256];
    int b = blockIdx.x, t = threadIdx.x;
    int base = b * SCAN_SEG + t * 4;
    int v[4]; int vsum = 0;
    #pragma unroll
    for (int j = 0; j < 4; ++j) { int idx = base + j; v[j] = (idx < NN) ? cnt[idx] : 0; vsum += v[j]; }
    sdata[t] = vsum; __syncthreads();
    int incl = vsum;
    for (int off = 1; off < 256; off <<= 1) {
        int add = (t >= off) ? sdata[t - off] : 0;
        __syncthreads();
        incl += add;
        sdata[t] = incl;
        __syncthreads();
    }
    int run = bsum[b] + (incl - vsum);
    #pragma unroll
    for (int j = 0; j < 4; ++j) {
        int idx = base + j;
        if (idx < NN) { rowstart[idx] = run; run += v[j]; cnt[idx] = 0; }  // zero cnt for reuse as cursor
    }
}

// ---------------- CSR fill: edat[pos] = {src, bits(norm)} ----------------

__global__ __launch_bounds__(256) void k_fill(const int* __restrict__ src, const int* __restrict__ dst,
                                              const float* __restrict__ w, const float* __restrict__ dinv,
                                              const int* __restrict__ rowstart, int* __restrict__ cnt,
                                              int2* __restrict__ edat) {
    int e = blockIdx.x * 256 + threadIdx.x;
    if (e < NE) {
        int s = src[e], d = dst[e];
        int pos = rowstart[d] + atomicAdd(&cnt[d], 1);
        float nw = dinv[s] * w[e] * dinv[d];
        edat[pos] = make_int2(s, __float_as_int(nw));
    }
}

// ---------------- GEMM: H = X @ W  (X [NN,128] f32, W [128,128] f32) ----------------
// block 256 = 8 row-threads x 32 col-threads; tile 64 rows x 128 cols; thread 8 rows x 4 cols.

__global__ __launch_bounds__(256) void k_gemm(const float* __restrict__ Xg, const float* __restrict__ Wg,
                                              float* __restrict__ Hg) {
    __shared__ float Ws[64][128];  // 32 KB: k-chunk x all cols
    __shared__ float Xs[64][64];   // 16 KB: rows x k-chunk

    int t  = threadIdx.x;
    int tx = t & 31;       // col group
    int ty = t >> 5;       // row group 0..7
    int c0 = tx * 4;
    int rowBase = blockIdx.x * 64;

    float4 acc[8];
    #pragma unroll
    for (int r = 0; r < 8; ++r) acc[r] = make_float4(0.f, 0.f, 0.f, 0.f);

    for (int kc = 0; kc < 128; kc += 64) {
        // load W chunk: 64x128 floats
        #pragma unroll
        for (int j = 0; j < 8; ++j) {
            int l  = (t + j * 256) * 4;
            int kr = l >> 7;
            int cc = l & 127;
            *(float4*)&Ws[kr][cc] = *(const float4*)&Wg[(kc + kr) * NC + cc];
        }
        // load X chunk: 64x64 floats
        #pragma unroll
        for (int j = 0; j < 4; ++j) {
            int l  = (t + j * 256) * 4;
            int rr = l >> 6;
            int kk = l & 63;
            int gr = rowBase + rr; if (gr > NN - 1) gr = NN - 1;
            *(float4*)&Xs[rr][kk] = *(const float4*)&Xg[(size_t)gr * NC + kc + kk];
        }
        __syncthreads();

        #pragma unroll 4
        for (int kk = 0; kk < 64; kk += 4) {
            float4 wv0 = *(const float4*)&Ws[kk + 0][c0];
            float4 wv1 = *(const float4*)&Ws[kk + 1][c0];
            float4 wv2 = *(const float4*)&Ws[kk + 2][c0];
            float4 wv3 = *(const float4*)&Ws[kk + 3][c0];
            #pragma unroll
            for (int r = 0; r < 8; ++r) {
                float4 xv = *(const float4*)&Xs[ty * 8 + r][kk];
                acc[r].x = fmaf(xv.x, wv0.x, acc[r].x); acc[r].y = fmaf(xv.x, wv0.y, acc[r].y);
                acc[r].z = fmaf(xv.x, wv0.z, acc[r].z); acc[r].w = fmaf(xv.x, wv0.w, acc[r].w);
                acc[r].x = fmaf(xv.y, wv1.x, acc[r].x); acc[r].y = fmaf(xv.y, wv1.y, acc[r].y);
                acc[r].z = fmaf(xv.y, wv1.z, acc[r].z); acc[r].w = fmaf(xv.y, wv1.w, acc[r].w);
                acc[r].x = fmaf(xv.z, wv2.x, acc[r].x); acc[r].y = fmaf(xv.z, wv2.y, acc[r].y);
                acc[r].z = fmaf(xv.z, wv2.z, acc[r].z); acc[r].w = fmaf(xv.z, wv2.w, acc[r].w);
                acc[r].x = fmaf(xv.w, wv3.x, acc[r].x); acc[r].y = fmaf(xv.w, wv3.y, acc[r].y);
                acc[r].z = fmaf(xv.w, wv3.z, acc[r].z); acc[r].w = fmaf(xv.w, wv3.w, acc[r].w);
            }
        }
        __syncthreads();
    }

    #pragma unroll
    for (int r = 0; r < 8; ++r) {
        int gr = rowBase + ty * 8 + r;
        if (gr < NN) *(float4*)&Hg[(size_t)gr * NC + c0] = acc[r];
    }
}

// ---------------- aggregation: out[d] = sum_e nrm*H[src] + dinv[d]^2*H[d] + b ----------------
// One 64-lane wave per node. 4 edges in flight: 16 lanes/edge, each lane owns 8
// channels (2x float4). Cross-group combine via __shfl_xor(16/32).

template <int RELU>
__global__ __launch_bounds__(256) void k_agg(const float* __restrict__ H, const int* __restrict__ rs,
                                             const int2* __restrict__ edat,
                                             const float* __restrict__ dinv, const float* __restrict__ bias,
                                             float* __restrict__ out) {
    int wid  = (blockIdx.x * 256 + threadIdx.x) >> 6;
    int lane = threadIdx.x & 63;
    if (wid >= NN) return;
    int node = wid;
    int g  = lane >> 4;   // edge group 0..3
    int cl = lane & 15;   // channel lane: owns channels cl*8 .. cl*8+7

    float4 acc0 = make_float4(0.f, 0.f, 0.f, 0.f);
    float4 acc1 = make_float4(0.f, 0.f, 0.f, 0.f);

    // self-loop (weight dinv^2) — group 0 only, counted once after the reduce
    if (g == 0) {
        float di = dinv[node];
        float s = di * di;
        const float4* hp = (const float4*)(H + (size_t)node * NC + cl * 8);
        float4 a = hp[0], b = hp[1];
        acc0.x = a.x * s; acc0.y = a.y * s; acc0.z = a.z * s; acc0.w = a.w * s;
        acc1.x = b.x * s; acc1.y = b.y * s; acc1.z = b.z * s; acc1.w = b.w * s;
    }

    int p0 = rs[node], p1 = rs[node + 1];
    for (int p = p0 + g; p < p1; p += 4) {
        int2 ed = edat[p];
        float nw = __int_as_float(ed.y);
        const float4* hp = (const float4*)(H + (size_t)ed.x * NC + cl * 8);
        float4 a = hp[0], b = hp[1];
        acc0.x = fmaf(nw, a.x, acc0.x); acc0.y = fmaf(nw, a.y, acc0.y);
        acc0.z = fmaf(nw, a.z, acc0.z); acc0.w = fmaf(nw, a.w, acc0.w);
        acc1.x = fmaf(nw, b.x, acc1.x); acc1.y = fmaf(nw, b.y, acc1.y);
        acc1.z = fmaf(nw, b.z, acc1.z); acc1.w = fmaf(nw, b.w, acc1.w);
    }

    // combine the 4 edge-groups: sum over lanes {cl, cl+16, cl+32, cl+48}
    #pragma unroll
    for (int m = 16; m <= 32; m <<= 1) {
        acc0.x += __shfl_xor(acc0.x, m); acc0.y += __shfl_xor(acc0.y, m);
        acc0.z += __shfl_xor(acc0.z, m); acc0.w += __shfl_xor(acc0.w, m);
        acc1.x += __shfl_xor(acc1.x, m); acc1.y += __shfl_xor(acc1.y, m);
        acc1.z += __shfl_xor(acc1.z, m); acc1.w += __shfl_xor(acc1.w, m);
    }

    if (g == 0) {
        const float4* bp = (const float4*)(bias + cl * 8);
        float4 bv0 = bp[0], bv1 = bp[1];
        acc0.x += bv0.x; acc0.y += bv0.y; acc0.z += bv0.z; acc0.w += bv0.w;
        acc1.x += bv1.x; acc1.y += bv1.y; acc1.z += bv1.z; acc1.w += bv1.w;
        if (RELU) {
            acc0.x = fmaxf(acc0.x, 0.f); acc0.y = fmaxf(acc0.y, 0.f);
            acc0.z = fmaxf(acc0.z, 0.f); acc0.w = fmaxf(acc0.w, 0.f);
            acc1.x = fmaxf(acc1.x, 0.f); acc1.y = fmaxf(acc1.y, 0.f);
            acc1.z = fmaxf(acc1.z, 0.f); acc1.w = fmaxf(acc1.w, 0.f);
        }
        float4* op = (float4*)(out + (size_t)node * NC + cl * 8);
        op[0] = acc0;
        op[1] = acc1;
    }
}

// ---------------- launch ----------------

static inline size_t alignup(size_t x) { return (x + 255) & ~(size_t)255; }

extern "C" void kernel_launch(void* const* d_in, const int* in_sizes, int n_in,
                              void* d_out, int out_size, void* d_ws, size_t ws_size,
                              hipStream_t stream) {
    const float* X  = (const float*)d_in[0];
    const int*   ei = (const int*)d_in[1];          // [2, NE]: row0 = src, row1 = dst
    const float* ew = (const float*)d_in[2];
    const float* W1 = (const float*)d_in[3]; const float* b1 = (const float*)d_in[4];
    const float* W2 = (const float*)d_in[5]; const float* b2 = (const float*)d_in[6];
    const float* W3 = (const float*)d_in[7]; const float* b3 = (const float*)d_in[8];
    float* out = (float*)d_out;

    const int* srcp = ei;
    const int* dstp = ei + NE;

    // workspace carve
    char* w = (char*)d_ws;
    size_t need = 0;
    auto carve = [&](size_t bytes) { char* p = w + need; need += alignup(bytes); return p; };
    float* deg      = (float*)carve(NN * 4);
    float* dinv     = (float*)carve(NN * 4);
    int*   cnt      = (int*)  carve(NN * 4);
    int*   rowstart = (int*)  carve((NN + 1) * 4);
    int*   bsum     = (int*)  carve(NB * 4);
    int2*  edat     = (int2*) carve((size_t)NE * 8);
    float* H        = (float*)carve((size_t)NN * NC * 4);
    float* A        = (float*)carve((size_t)NN * NC * 4);
    if (need > ws_size) return;  // workspace too small -> visible validation failure

    const int gN = (NN + 255) / 256;
    const int gE = (NE + 255) / 256;
    const int gGemm = (NN + 63) / 64;
    const int gAgg  = (NN * 64 + 255) / 256;  // one wave per node

    // build normalization + CSR (once; reused by all 3 layers)
    k_init<<<gN, 256, 0, stream>>>(deg, cnt);
    k_degcount<<<gE, 256, 0, stream>>>(dstp, ew, deg, cnt);
    k_dinv<<<gN, 256, 0, stream>>>(deg, dinv);
    k_scan1<<<NB, 256, 0, stream>>>(cnt, bsum);
    k_scan2<<<1, 64, 0, stream>>>(bsum, rowstart);
    k_scan3<<<NB, 256, 0, stream>>>(cnt, bsum, rowstart);
    k_fill<<<gE, 256, 0, stream>>>(srcp, dstp, ew, dinv, rowstart, cnt, edat);

    // layer 1
    k_gemm<<<gGemm, 256, 0, stream>>>(X, W1, H);
    k_agg<1><<<gAgg, 256, 0, stream>>>(H, rowstart, edat, dinv, b1, A);
    // layer 2
    k_gemm<<<gGemm, 256, 0, stream>>>(A, W2, H);
    k_agg<1><<<gAgg, 256, 0, stream>>>(H, rowstart, edat, dinv, b2, A);
    // layer 3
    k_gemm<<<gGemm, 256, 0, stream>>>(A, W3, H);
    k_agg<0><<<gAgg, 256, 0, stream>>>(H, rowstart, edat, dinv, b3, out);
}

// Round 3
// 645.009 us; speedup vs baseline: 1.3904x; 1.1440x over previous
//
#include <hip/hip_runtime.h>
#include <hip/hip_bf16.h>
#include <cstdint>

#define NN 100000
#define NE 1600000
#define NC 128

constexpr int SCAN_SEG = 1024;
constexpr int NB = (NN + SCAN_SEG - 1) / SCAN_SEG; // 98

// ---------------- CSR build ----------------

__global__ __launch_bounds__(256) void k_init(int* __restrict__ cnt) {
    int i = blockIdx.x * 256 + threadIdx.x;
    if (i < NN) cnt[i] = 0;
}

// one int atomic per edge; returned old value = within-row slot
__global__ __launch_bounds__(256) void k_count(const int* __restrict__ dst, int* __restrict__ cnt,
                                               int* __restrict__ slot) {
    int e = blockIdx.x * 256 + threadIdx.x;
    if (e < NE) slot[e] = atomicAdd(&cnt[dst[e]], 1);
}

// ---------------- exclusive scan of cnt -> rowstart ----------------

__global__ __launch_bounds__(256) void k_scan1(const int* __restrict__ cnt, int* __restrict__ bsum) {
    __shared__ int sdata[256];
    int b = blockIdx.x, t = threadIdx.x;
    int base = b * SCAN_SEG + t * 4;
    int s = 0;
    #pragma unroll
    for (int j = 0; j < 4; ++j) { int idx = base + j; if (idx < NN) s += cnt[idx]; }
    sdata[t] = s; __syncthreads();
    for (int off = 128; off > 0; off >>= 1) {
        if (t < off) sdata[t] += sdata[t + off];
        __syncthreads();
    }
    if (t == 0) bsum[b] = sdata[0];
}

__global__ void k_scan2(int* __restrict__ bsum, int* __restrict__ rowstart) {
    if (threadIdx.x == 0 && blockIdx.x == 0) {
        int run = 0;
        for (int i = 0; i < NB; ++i) { int v = bsum[i]; bsum[i] = run; run += v; }
        rowstart[NN] = run;  // == NE
    }
}

__global__ __launch_bounds__(256) void k_scan3(const int* __restrict__ cnt, const int* __restrict__ bsum,
                                               int* __restrict__ rowstart) {
    __shared__ int sdata[256];
    int b = blockIdx.x, t = threadIdx.x;
    int base = b * SCAN_SEG + t * 4;
    int v[4]; int vsum = 0;
    #pragma unroll
    for (int j = 0; j < 4; ++j) { int idx = base + j; v[j] = (idx < NN) ? cnt[idx] : 0; vsum += v[j]; }
    sdata[t] = vsum; __syncthreads();
    int incl = vsum;
    for (int off = 1; off < 256; off <<= 1) {
        int add = (t >= off) ? sdata[t - off] : 0;
        __syncthreads();
        incl += add;
        sdata[t] = incl;
        __syncthreads();
    }
    int run = bsum[b] + (incl - vsum);
    #pragma unroll
    for (int j = 0; j < 4; ++j) {
        int idx = base + j;
        if (idx < NN) { rowstart[idx] = run; run += v[j]; }
    }
}

// ---------------- CSR fill (no atomics): edat[pos] = {src, bits(w)} ----------------

__global__ __launch_bounds__(256) void k_fill(const int* __restrict__ src, const int* __restrict__ dst,
                                              const float* __restrict__ w, const int* __restrict__ rowstart,
                                              const int* __restrict__ slot, int2* __restrict__ edat) {
    int e = blockIdx.x * 256 + threadIdx.x;
    if (e < NE) {
        int pos = rowstart[dst[e]] + slot[e];
        edat[pos] = make_int2(src[e], __float_as_int(w[e]));
    }
}

// ---------------- deg -> dinv (no atomics): deg = 1 + sum_row(w) ----------------

__global__ __launch_bounds__(256) void k_degdinv(const int* __restrict__ rs, const int2* __restrict__ edat,
                                                 float* __restrict__ dinv) {
    int i = blockIdx.x * 256 + threadIdx.x;
    if (i < NN) {
        float dg = 1.0f;  // self-loop weight
        int p1 = rs[i + 1];
        for (int p = rs[i]; p < p1; ++p) dg += __int_as_float(edat[p].y);
        dinv[i] = (dg > 0.0f) ? (1.0f / sqrtf(fmaxf(dg, 1e-12f))) : 0.0f;
    }
}

// ---------------- norm: edat[p].y = bits(dinv[src] * w)  (dinv[dst] applied in k_agg) ----------------

__global__ __launch_bounds__(256) void k_norm(const float* __restrict__ dinv, int2* __restrict__ edat) {
    int p = blockIdx.x * 256 + threadIdx.x;
    if (p < NE) {
        int2 ed = edat[p];
        edat[p].y = __float_as_int(dinv[ed.x] * __int_as_float(ed.y));
    }
}

// ---------------- GEMM: H = X @ W  (X [NN,128] f32, W [128,128] f32) ----------------
// block 256 = 8 row-threads x 32 col-threads; tile 64 rows x 128 cols; thread 8 rows x 4 cols.

__global__ __launch_bounds__(256) void k_gemm(const float* __restrict__ Xg, const float* __restrict__ Wg,
                                              float* __restrict__ Hg) {
    __shared__ float Ws[64][128];  // 32 KB: k-chunk x all cols
    __shared__ float Xs[64][64];   // 16 KB: rows x k-chunk

    int t  = threadIdx.x;
    int tx = t & 31;       // col group
    int ty = t >> 5;       // row group 0..7
    int c0 = tx * 4;
    int rowBase = blockIdx.x * 64;

    float4 acc[8];
    #pragma unroll
    for (int r = 0; r < 8; ++r) acc[r] = make_float4(0.f, 0.f, 0.f, 0.f);

    for (int kc = 0; kc < 128; kc += 64) {
        #pragma unroll
        for (int j = 0; j < 8; ++j) {
            int l  = (t + j * 256) * 4;
            int kr = l >> 7;
            int cc = l & 127;
            *(float4*)&Ws[kr][cc] = *(const float4*)&Wg[(kc + kr) * NC + cc];
        }
        #pragma unroll
        for (int j = 0; j < 4; ++j) {
            int l  = (t + j * 256) * 4;
            int rr = l >> 6;
            int kk = l & 63;
            int gr = rowBase + rr; if (gr > NN - 1) gr = NN - 1;
            *(float4*)&Xs[rr][kk] = *(const float4*)&Xg[(size_t)gr * NC + kc + kk];
        }
        __syncthreads();

        #pragma unroll 4
        for (int kk = 0; kk < 64; kk += 4) {
            float4 wv0 = *(const float4*)&Ws[kk + 0][c0];
            float4 wv1 = *(const float4*)&Ws[kk + 1][c0];
            float4 wv2 = *(const float4*)&Ws[kk + 2][c0];
            float4 wv3 = *(const float4*)&Ws[kk + 3][c0];
            #pragma unroll
            for (int r = 0; r < 8; ++r) {
                float4 xv = *(const float4*)&Xs[ty * 8 + r][kk];
                acc[r].x = fmaf(xv.x, wv0.x, acc[r].x); acc[r].y = fmaf(xv.x, wv0.y, acc[r].y);
                acc[r].z = fmaf(xv.x, wv0.z, acc[r].z); acc[r].w = fmaf(xv.x, wv0.w, acc[r].w);
                acc[r].x = fmaf(xv.y, wv1.x, acc[r].x); acc[r].y = fmaf(xv.y, wv1.y, acc[r].y);
                acc[r].z = fmaf(xv.y, wv1.z, acc[r].z); acc[r].w = fmaf(xv.y, wv1.w, acc[r].w);
                acc[r].x = fmaf(xv.z, wv2.x, acc[r].x); acc[r].y = fmaf(xv.z, wv2.y, acc[r].y);
                acc[r].z = fmaf(xv.z, wv2.z, acc[r].z); acc[r].w = fmaf(xv.z, wv2.w, acc[r].w);
                acc[r].x = fmaf(xv.w, wv3.x, acc[r].x); acc[r].y = fmaf(xv.w, wv3.y, acc[r].y);
                acc[r].z = fmaf(xv.w, wv3.z, acc[r].z); acc[r].w = fmaf(xv.w, wv3.w, acc[r].w);
            }
        }
        __syncthreads();
    }

    #pragma unroll
    for (int r = 0; r < 8; ++r) {
        int gr = rowBase + ty * 8 + r;
        if (gr < NN) *(float4*)&Hg[(size_t)gr * NC + c0] = acc[r];
    }
}

// ---------------- aggregation: out[d] = dinv[d]*(sum_e nrm'*H[src] + dinv[d]*H[d]) + b ----------------
// One 64-lane wave per node. 4 edges in flight: 16 lanes/edge, each lane owns 8
// channels (2x float4). Cross-group combine via __shfl_xor(16/32).

template <int RELU>
__global__ __launch_bounds__(256) void k_agg(const float* __restrict__ H, const int* __restrict__ rs,
                                             const int2* __restrict__ edat,
                                             const float* __restrict__ dinv, const float* __restrict__ bias,
                                             float* __restrict__ out) {
    int wid  = (blockIdx.x * 256 + threadIdx.x) >> 6;
    int lane = threadIdx.x & 63;
    if (wid >= NN) return;
    int node = wid;
    int g  = lane >> 4;   // edge group 0..3
    int cl = lane & 15;   // channel lane: owns channels cl*8 .. cl*8+7

    float di = dinv[node];
    float4 acc0 = make_float4(0.f, 0.f, 0.f, 0.f);
    float4 acc1 = make_float4(0.f, 0.f, 0.f, 0.f);

    // self-loop contribution (before the final *di): di * H[node]
    if (g == 0) {
        const float4* hp = (const float4*)(H + (size_t)node * NC + cl * 8);
        float4 a = hp[0], b = hp[1];
        acc0.x = a.x * di; acc0.y = a.y * di; acc0.z = a.z * di; acc0.w = a.w * di;
        acc1.x = b.x * di; acc1.y = b.y * di; acc1.z = b.z * di; acc1.w = b.w * di;
    }

    int p0 = rs[node], p1 = rs[node + 1];
    for (int p = p0 + g; p < p1; p += 4) {
        int2 ed = edat[p];
        float nw = __int_as_float(ed.y);
        const float4* hp = (const float4*)(H + (size_t)ed.x * NC + cl * 8);
        float4 a = hp[0], b = hp[1];
        acc0.x = fmaf(nw, a.x, acc0.x); acc0.y = fmaf(nw, a.y, acc0.y);
        acc0.z = fmaf(nw, a.z, acc0.z); acc0.w = fmaf(nw, a.w, acc0.w);
        acc1.x = fmaf(nw, b.x, acc1.x); acc1.y = fmaf(nw, b.y, acc1.y);
        acc1.z = fmaf(nw, b.z, acc1.z); acc1.w = fmaf(nw, b.w, acc1.w);
    }

    #pragma unroll
    for (int m = 16; m <= 32; m <<= 1) {
        acc0.x += __shfl_xor(acc0.x, m); acc0.y += __shfl_xor(acc0.y, m);
        acc0.z += __shfl_xor(acc0.z, m); acc0.w += __shfl_xor(acc0.w, m);
        acc1.x += __shfl_xor(acc1.x, m); acc1.y += __shfl_xor(acc1.y, m);
        acc1.z += __shfl_xor(acc1.z, m); acc1.w += __shfl_xor(acc1.w, m);
    }

    if (g == 0) {
        const float4* bp = (const float4*)(bias + cl * 8);
        float4 bv0 = bp[0], bv1 = bp[1];
        acc0.x = fmaf(acc0.x, di, bv0.x); acc0.y = fmaf(acc0.y, di, bv0.y);
        acc0.z = fmaf(acc0.z, di, bv0.z); acc0.w = fmaf(acc0.w, di, bv0.w);
        acc1.x = fmaf(acc1.x, di, bv1.x); acc1.y = fmaf(acc1.y, di, bv1.y);
        acc1.z = fmaf(acc1.z, di, bv1.z); acc1.w = fmaf(acc1.w, di, bv1.w);
        if (RELU) {
            acc0.x = fmaxf(acc0.x, 0.f); acc0.y = fmaxf(acc0.y, 0.f);
            acc0.z = fmaxf(acc0.z, 0.f); acc0.w = fmaxf(acc0.w, 0.f);
            acc1.x = fmaxf(acc1.x, 0.f); acc1.y = fmaxf(acc1.y, 0.f);
            acc1.z = fmaxf(acc1.z, 0.f); acc1.w = fmaxf(acc1.w, 0.f);
        }
        float4* op = (float4*)(out + (size_t)node * NC + cl * 8);
        op[0] = acc0;
        op[1] = acc1;
    }
}

// ---------------- launch ----------------

static inline size_t alignup(size_t x) { return (x + 255) & ~(size_t)255; }

extern "C" void kernel_launch(void* const* d_in, const int* in_sizes, int n_in,
                              void* d_out, int out_size, void* d_ws, size_t ws_size,
                              hipStream_t stream) {
    const float* X  = (const float*)d_in[0];
    const int*   ei = (const int*)d_in[1];          // [2, NE]: row0 = src, row1 = dst
    const float* ew = (const float*)d_in[2];
    const float* W1 = (const float*)d_in[3]; const float* b1 = (const float*)d_in[4];
    const float* W2 = (const float*)d_in[5]; const float* b2 = (const float*)d_in[6];
    const float* W3 = (const float*)d_in[7]; const float* b3 = (const float*)d_in[8];
    float* out = (float*)d_out;

    const int* srcp = ei;
    const int* dstp = ei + NE;

    // workspace carve
    char* w = (char*)d_ws;
    size_t need = 0;
    auto carve = [&](size_t bytes) { char* p = w + need; need += alignup(bytes); return p; };
    float* dinv     = (float*)carve(NN * 4);
    int*   cnt      = (int*)  carve(NN * 4);
    int*   rowstart = (int*)  carve((NN + 1) * 4);
    int*   bsum     = (int*)  carve(NB * 4);
    int*   slot     = (int*)  carve((size_t)NE * 4);
    int2*  edat     = (int2*) carve((size_t)NE * 8);
    float* H        = (float*)carve((size_t)NN * NC * 4);
    float* A        = (float*)carve((size_t)NN * NC * 4);
    if (need > ws_size) return;  // workspace too small -> visible validation failure

    const int gN = (NN + 255) / 256;
    const int gE = (NE + 255) / 256;
    const int gGemm = (NN + 63) / 64;
    const int gAgg  = (NN * 64 + 255) / 256;  // one wave per node

    // build normalization + CSR (once; reused by all 3 layers)
    k_init<<<gN, 256, 0, stream>>>(cnt);
    k_count<<<gE, 256, 0, stream>>>(dstp, cnt, slot);
    k_scan1<<<NB, 256, 0, stream>>>(cnt, bsum);
    k_scan2<<<1, 64, 0, stream>>>(bsum, rowstart);
    k_scan3<<<NB, 256, 0, stream>>>(cnt, bsum, rowstart);
    k_fill<<<gE, 256, 0, stream>>>(srcp, dstp, ew, rowstart, slot, edat);
    k_degdinv<<<gN, 256, 0, stream>>>(rowstart, edat, dinv);
    k_norm<<<gE, 256, 0, stream>>>(dinv, edat);

    // layer 1
    k_gemm<<<gGemm, 256, 0, stream>>>(X, W1, H);
    k_agg<1><<<gAgg, 256, 0, stream>>>(H, rowstart, edat, dinv, b1, A);
    // layer 2
    k_gemm<<<gGemm, 256, 0, stream>>>(A, W2, H);
    k_agg<1><<<gAgg, 256, 0, stream>>>(H, rowstart, edat, dinv, b2, A);
    // layer 3
    k_gemm<<<gGemm, 256, 0, stream>>>(A, W3, H);
    k_agg<0><<<gAgg, 256, 0, stream>>>(H, rowstart, edat, dinv, b3, out);
}